// Round 15
// baseline (1320.261 us; speedup 1.0000x reference)
//
#include <hip/hip_runtime.h>

#define U_N 100000
#define I_N 50000
#define D_N 64
#define B_N 4
#define E_N 2000000

#define EDGES   (B_N * E_N)            // 8,000,000 edge-entries per side
#define NBLK    256                    // pass-A partition blocks (32 per XCD)
#define EPB     (EDGES / NBLK)         // 31,250 entries per block (exact)
#define NBKT    625                    // buckets per side (both sides)
#define CAP     13568                  // bucket capacity (mean 12800, +6.8 sigma)
#define XSTR2   69                     // xs stride (dwords): 4*69%32=20 -> ~2-way

// user side: BKT_CH=20 chunks/bucket (625*20*8 = 100k rows)
// item side: BKT_CH=10 chunks/bucket (625*10*8 =  50k rows)
// bin-in-bucket = cib*32 + ((k&7)<<2) | behavior   (payA_L, u16)
// payA_K = bf16val-sans-sign(15b)<<17 | src(17b)

// ---------------------------------------------------------------------------
// Pass 0: convert both embedding tables to bf16 (RNE).
// ---------------------------------------------------------------------------
__global__ __launch_bounds__(256) void cvt_kernel(const float* __restrict__ ue,
                                                  const float* __restrict__ ie,
                                                  unsigned short* __restrict__ u16,
                                                  unsigned short* __restrict__ i16) {
    int i = blockIdx.x * 256 + threadIdx.x;
    int nu = U_N * D_N;
    int ni = I_N * D_N;
    if (i < nu) {
        unsigned u = __float_as_uint(ue[i]);
        u += 0x7FFFu + ((u >> 16) & 1u);
        u16[i] = (unsigned short)(u >> 16);
    } else if (i < nu + ni) {
        int j = i - nu;
        unsigned u = __float_as_uint(ie[j]);
        u += 0x7FFFu + ((u >> 16) & 1u);
        i16[j] = (unsigned short)(u >> 16);
    }
}

// ---------------------------------------------------------------------------
// Pass A1: per-(block, bucket) histogram. LDS h[625].
// ---------------------------------------------------------------------------
template <int BKT_CH>
__global__ __launch_bounds__(1024) void histA_kernel(const int* __restrict__ keys,
                                                     int* __restrict__ cntA) {
    __shared__ int h[NBKT];
    for (int i = threadIdx.x; i < NBKT; i += 1024) h[i] = 0;
    __syncthreads();
    int lb = ((blockIdx.x & 7) << 5) | (blockIdx.x >> 3);   // XCD-major
    int base = lb * EPB;
    for (int i = threadIdx.x; i < EPB; i += 1024)
        atomicAdd(&h[(keys[base + i] >> 3) / BKT_CH], 1);
    __syncthreads();
    int* row = cntA + (size_t)lb * NBKT;
    for (int i = threadIdx.x; i < NBKT; i += 1024) row[i] = h[i];
}

// ---------------------------------------------------------------------------
// Pass A2: bucket totals -> exclusive scan -> per-block cursors in place.
// ---------------------------------------------------------------------------
__global__ __launch_bounds__(1024) void scanA_kernel(int* __restrict__ cntA,
                                                     int* __restrict__ offBkt) {
    int t = threadIdx.x;
    int s = 0;
    if (t < NBKT)
        for (int lb = 0; lb < NBLK; ++lb) s += cntA[(size_t)lb * NBKT + t];
    __shared__ int sm[1024];
    sm[t] = (t < NBKT) ? s : 0;
    __syncthreads();
    for (int o = 1; o < 1024; o <<= 1) {
        int a = (t >= o) ? sm[t - o] : 0;
        __syncthreads(); sm[t] += a; __syncthreads();
    }
    int pre = sm[t] - ((t < NBKT) ? s : 0);
    if (t < NBKT) {
        offBkt[t] = pre;
        int run = pre;
        for (int lb = 0; lb < NBLK; ++lb) {
            int c = cntA[(size_t)lb * NBKT + t];
            cntA[(size_t)lb * NBKT + t] = run;
            run += c;
        }
    }
    if (t == 0) offBkt[NBKT] = EDGES;
}

// ---------------------------------------------------------------------------
// Pass A3: coarse placement into buckets. LDS cursors (625), zero global
// atomics; frontier ~2x625 lines/block -> per-XCD L2-resident (~2.5 MB).
// ---------------------------------------------------------------------------
template <int BKT_CH>
__global__ __launch_bounds__(1024) void cplaceA_kernel(
        const int* __restrict__ keys,
        const int* __restrict__ srcs,
        const float* __restrict__ vals,
        const int* __restrict__ curA,
        unsigned* __restrict__ payA_K,
        unsigned short* __restrict__ payA_L) {
    __shared__ int cur[NBKT];
    int lb = ((blockIdx.x & 7) << 5) | (blockIdx.x >> 3);
    const int* crow = curA + (size_t)lb * NBKT;
    for (int i = threadIdx.x; i < NBKT; i += 1024) cur[i] = crow[i];
    __syncthreads();
    int base = lb * EPB;
    int b = lb >> 6;                     // behavior: 64 blocks per behavior
    for (int i = threadIdx.x; i < EPB; i += 1024) {
        int gi = base + i;
        int k = keys[gi];
        int chunk = k >> 3;
        int bkt = chunk / BKT_CH;        // constant divisor -> magic mul
        int cib = chunk - bkt * BKT_CH;
        unsigned u = __float_as_uint(vals[gi]);   // vals > 0 -> sign bit 0
        u += 0x7FFFu + ((u >> 16) & 1u);
        unsigned bf15 = (u >> 16) & 0x7FFFu;
        int pos = atomicAdd(&cur[bkt], 1);
        payA_K[pos] = (bf15 << 17) | (unsigned)srcs[gi];
        payA_L[pos] = (unsigned short)((cib << 5) | ((k & 7) << 2) | b);
    }
}

// ---------------------------------------------------------------------------
// Pass B (fused): one block per bucket. In-LDS counting sort by bin, then
// barrier-free phases: 2 chunks/phase, 8 waves each; quad-row register
// accumulate from LDS st2; d-major xs; 64x64 transform + sigmoid + mean.
// LDS ~76 KB -> 2 blocks/CU.
// ---------------------------------------------------------------------------
template <int BKT_CH>
__global__ __launch_bounds__(1024) void fusedB_kernel(
        const unsigned* __restrict__ payA_K,
        const unsigned short* __restrict__ payA_L,
        const int* __restrict__ offBkt,
        const unsigned short* __restrict__ emb16,
        const float* __restrict__ W,
        float* __restrict__ embs,        // [B][nrows][64] <- sigmoid(x@W)
        float* __restrict__ mean_out,    // [nrows][64]    <- sigmoid(mean@W)
        int nrows) {
    const int NBIN = BKT_CH * 32;
    const int NPH  = (BKT_CH + 1) / 2;
    int bk = blockIdx.x;
    int base = offBkt[bk], n = offBkt[bk + 1] - base;
    int t = threadIdx.x, w = t >> 6, lane = t & 63;

    __shared__ unsigned st2[CAP];        // 53 KB sorted keys
    __shared__ float xs[64 * XSTR2];     // 17.7 KB d-major accumulators
    __shared__ int h[NBIN];              // counts -> cursors
    __shared__ int binst[NBIN + 1];

    if (n <= CAP) {
        for (int i = t; i < NBIN; i += 1024) h[i] = 0;
        __syncthreads();
        for (int i = t; i < n; i += 1024)
            atomicAdd(&h[payA_L[base + i]], 1);
        __syncthreads();
        if (t == 0) {                    // serial prefix (NBIN<=640, ~2 us)
            int s = 0;
            for (int b2 = 0; b2 < NBIN; ++b2) {
                binst[b2] = s; s += h[b2]; h[b2] = binst[b2];
            }
            binst[NBIN] = s;
        }
        __syncthreads();
        for (int i = t; i < n; i += 1024) {
            int pos = atomicAdd(&h[payA_L[base + i]], 1);
            st2[pos] = payA_K[base + i];
        }
        __syncthreads();

        // Phases: chunk cib = 2p + (w>>3); wave-local row wl = w&7.
        int qt = lane >> 4, ql = lane & 15;
        for (int p = 0; p < NPH; ++p) {
            int cib = 2 * p + (w >> 3);
            if (cib < BKT_CH) {
                int wl = w & 7;
                int binb = cib * 32 + wl * 4;
                int colbase = (w >> 3) * 32 + wl * 4;
                float4 a0, a1, a2, a3;
#define ACC_BIN(AQ, Q)                                                        \
                {                                                             \
                    int s0 = binst[binb + (Q)];                               \
                    int s1 = binst[binb + (Q) + 1];                           \
                    AQ = make_float4(0.f, 0.f, 0.f, 0.f);                     \
                    for (int j = s0; j < s1; j += 4) {                        \
                        int idx = j + qt;                                     \
                        int jj = idx < s1 ? idx : s1 - 1;                     \
                        unsigned pv = st2[jj];                                \
                        float v = (idx < s1)                                  \
                            ? __uint_as_float((pv & 0xFFFE0000u) >> 1) : 0.f; \
                        uint2 x = *((const uint2*)(emb16 +                    \
                                      (size_t)(pv & 0x1FFFFu) * 64) + ql);    \
                        AQ.x = fmaf(v, __uint_as_float(x.x << 16), AQ.x);     \
                        AQ.y = fmaf(v, __uint_as_float(x.x & 0xFFFF0000u), AQ.y); \
                        AQ.z = fmaf(v, __uint_as_float(x.y << 16), AQ.z);     \
                        AQ.w = fmaf(v, __uint_as_float(x.y & 0xFFFF0000u), AQ.w); \
                    }                                                         \
                    AQ.x += __shfl_xor(AQ.x, 16); AQ.x += __shfl_xor(AQ.x, 32); \
                    AQ.y += __shfl_xor(AQ.y, 16); AQ.y += __shfl_xor(AQ.y, 32); \
                    AQ.z += __shfl_xor(AQ.z, 16); AQ.z += __shfl_xor(AQ.z, 32); \
                    AQ.w += __shfl_xor(AQ.w, 16); AQ.w += __shfl_xor(AQ.w, 32); \
                }
                ACC_BIN(a0, 0)
                ACC_BIN(a1, 1)
                ACC_BIN(a2, 2)
                ACC_BIN(a3, 3)
#undef ACC_BIN
                if (qt == 0) {           // intra-wave dep with transform reads
                    *(float4*)&xs[(4 * ql + 0) * XSTR2 + colbase] =
                        make_float4(a0.x, a1.x, a2.x, a3.x);
                    *(float4*)&xs[(4 * ql + 1) * XSTR2 + colbase] =
                        make_float4(a0.y, a1.y, a2.y, a3.y);
                    *(float4*)&xs[(4 * ql + 2) * XSTR2 + colbase] =
                        make_float4(a0.z, a1.z, a2.z, a3.z);
                    *(float4*)&xs[(4 * ql + 3) * XSTR2 + colbase] =
                        make_float4(a0.w, a1.w, a2.w, a3.w);
                }
                float y[4] = {0.f, 0.f, 0.f, 0.f};
#pragma unroll 4
                for (int d = 0; d < 64; ++d) {
                    float4 xq = *(const float4*)&xs[d * XSTR2 + colbase];
                    float wv = W[d * 64 + lane];
                    y[0] = fmaf(xq.x, wv, y[0]);
                    y[1] = fmaf(xq.y, wv, y[1]);
                    y[2] = fmaf(xq.z, wv, y[2]);
                    y[3] = fmaf(xq.w, wv, y[3]);
                }
                int row = (bk * BKT_CH + cib) * 8 + wl;
#pragma unroll
                for (int q = 0; q < 4; ++q)
                    embs[((long long)q * nrows + row) * 64 + lane] =
                        1.f / (1.f + __expf(-y[q]));
                float m = 0.25f * (y[0] + y[1] + y[2] + y[3]);
                mean_out[(long long)row * 64 + lane] =
                    1.f / (1.f + __expf(-m));
            }
        }
    } else {
        // Fallback (never for this input): LDS-atomic accumulate per phase,
        // scanning the bucket segment from global. Block-uniform path.
        for (int p = 0; p < NPH; ++p) {
            for (int i = t; i < 64 * XSTR2; i += 1024) xs[i] = 0.f;
            __syncthreads();
            for (int i = w; i < n; i += 16) {
                unsigned L = payA_L[base + i];
                int cib = (int)(L >> 5);
                if ((cib >> 1) == p) {
                    unsigned P = payA_K[base + i];
                    float v = __uint_as_float((P & 0xFFFE0000u) >> 1);
                    float x = __uint_as_float(
                        (unsigned)emb16[(size_t)(P & 0x1FFFFu) * 64 + lane] << 16);
                    int col = (cib & 1) * 32 + (int)(L & 31u);
                    atomicAdd(&xs[lane * XSTR2 + col], v * x);
                }
            }
            __syncthreads();
            int cib = 2 * p + (w >> 3);
            if (cib < BKT_CH) {
                int wl = w & 7;
                int colbase = (w >> 3) * 32 + wl * 4;
                float y[4] = {0.f, 0.f, 0.f, 0.f};
                for (int d = 0; d < 64; ++d) {
                    float4 xq = *(const float4*)&xs[d * XSTR2 + colbase];
                    float wv = W[d * 64 + lane];
                    y[0] = fmaf(xq.x, wv, y[0]);
                    y[1] = fmaf(xq.y, wv, y[1]);
                    y[2] = fmaf(xq.z, wv, y[2]);
                    y[3] = fmaf(xq.w, wv, y[3]);
                }
                int row = (bk * BKT_CH + cib) * 8 + wl;
#pragma unroll
                for (int q = 0; q < 4; ++q)
                    embs[((long long)q * nrows + row) * 64 + lane] =
                        1.f / (1.f + __expf(-y[q]));
                float m = 0.25f * (y[0] + y[1] + y[2] + y[3]);
                mean_out[(long long)row * 64 + lane] =
                    1.f / (1.f + __expf(-m));
            }
            __syncthreads();
        }
    }
}

// ---------------------------------------------------------------------------
// Deep fallback: atomic scatter + separate transform (only if ws too small).
// ---------------------------------------------------------------------------
__global__ void scatter_atomic_kernel(const float* __restrict__ user_emb,
                                      const float* __restrict__ item_emb,
                                      const int* __restrict__ rows,
                                      const int* __restrict__ cols,
                                      const float* __restrict__ vals,
                                      float* __restrict__ stack_u,
                                      float* __restrict__ stack_i) {
    long long tid = (long long)blockIdx.x * blockDim.x + threadIdx.x;
    long long e  = tid >> 4;
    int lane = (int)(tid & 15);
    if (e >= (long long)EDGES) return;
    int b = (int)(e / E_N);
    int r = rows[e];
    int c = cols[e];
    float v = vals[e];
    const float4* irow = (const float4*)(item_emb + (long long)c * D_N);
    const float4* urow = (const float4*)(user_emb + (long long)r * D_N);
    float4 iv = irow[lane];
    float4 uv = urow[lane];
    float* du = stack_u + ((long long)b * U_N + r) * D_N + lane * 4;
    float* di = stack_i + ((long long)b * I_N + c) * D_N + lane * 4;
    atomicAdd(du + 0, v * iv.x);
    atomicAdd(du + 1, v * iv.y);
    atomicAdd(du + 2, v * iv.z);
    atomicAdd(du + 3, v * iv.w);
    atomicAdd(di + 0, v * uv.x);
    atomicAdd(di + 1, v * uv.y);
    atomicAdd(di + 2, v * uv.z);
    atomicAdd(di + 3, v * uv.w);
}

template <int NROWS>
__global__ __launch_bounds__(64) void transform_kernel(
        float* __restrict__ stack,
        const float* __restrict__ W,
        float* __restrict__ mean_out) {
    const int row = blockIdx.x;
    const int j   = threadIdx.x;
    __shared__ float xs[B_N][D_N];
#pragma unroll
    for (int b = 0; b < B_N; ++b)
        xs[b][j] = stack[((long long)b * NROWS + row) * D_N + j];
    __syncthreads();
    float acc[B_N] = {0.f, 0.f, 0.f, 0.f};
#pragma unroll 8
    for (int d = 0; d < D_N; ++d) {
        float w = W[d * D_N + j];
#pragma unroll
        for (int b = 0; b < B_N; ++b)
            acc[b] += xs[b][d] * w;
    }
    float m = 0.25f * (acc[0] + acc[1] + acc[2] + acc[3]);
#pragma unroll
    for (int b = 0; b < B_N; ++b)
        stack[((long long)b * NROWS + row) * D_N + j] =
            1.0f / (1.0f + __expf(-acc[b]));
    mean_out[(long long)row * D_N + j] = 1.0f / (1.0f + __expf(-m));
}

// ---------------------------------------------------------------------------
extern "C" void kernel_launch(void* const* d_in, const int* in_sizes, int n_in,
                              void* d_out, int out_size, void* d_ws, size_t ws_size,
                              hipStream_t stream) {
    const float* user_emb = (const float*)d_in[0];
    const float* item_emb = (const float*)d_in[1];
    const int*   rows     = (const int*)  d_in[2];
    const int*   cols     = (const int*)  d_in[3];
    const float* vals     = (const float*)d_in[4];
    const float* u_w      = (const float*)d_in[5];
    const float* i_w      = (const float*)d_in[6];

    float* out = (float*)d_out;
    float* user_mean = out;
    float* item_mean = out + (long long)U_N * D_N;
    float* stack_u   = item_mean + (long long)I_N * D_N;     // user_embs out
    float* stack_i   = stack_u + (long long)B_N * U_N * D_N; // item_embs out

    // Workspace (~68 MB): payA_K | payA_L | user16 | item16 | cntA | offBkt
    unsigned* payA_K = (unsigned*)d_ws;                            // 32 MB
    unsigned short* payA_L = (unsigned short*)(payA_K + EDGES);    // 16 MB
    unsigned short* user16 = payA_L + (size_t)EDGES;               // 12.8 MB
    unsigned short* item16 = user16 + (size_t)U_N * D_N;           // 6.4 MB
    int* cntA   = (int*)(item16 + (size_t)I_N * D_N);              // 640 KB
    int* offBkt = cntA + (size_t)NBLK * NBKT;                      // 2.5 KB
    size_t needed = ((char*)(offBkt + NBKT + 1)) - (char*)d_ws;

    if (ws_size >= needed) {
        int ncvt = (U_N + I_N) * D_N;
        cvt_kernel<<<(ncvt + 255) / 256, 256, 0, stream>>>(user_emb, item_emb,
                                                           user16, item16);
        // ---- user side: keys=rows, gathers item table; 625 x 20 chunks ----
        histA_kernel<20><<<NBLK, 1024, 0, stream>>>(rows, cntA);
        scanA_kernel<<<1, 1024, 0, stream>>>(cntA, offBkt);
        cplaceA_kernel<20><<<NBLK, 1024, 0, stream>>>(rows, cols, vals, cntA,
                                                      payA_K, payA_L);
        fusedB_kernel<20><<<NBKT, 1024, 0, stream>>>(payA_K, payA_L, offBkt,
                                                     item16, u_w,
                                                     stack_u, user_mean, U_N);
        // ---- item side: keys=cols, gathers user table; 625 x 10 chunks ----
        histA_kernel<10><<<NBLK, 1024, 0, stream>>>(cols, cntA);
        scanA_kernel<<<1, 1024, 0, stream>>>(cntA, offBkt);
        cplaceA_kernel<10><<<NBLK, 1024, 0, stream>>>(cols, rows, vals, cntA,
                                                      payA_K, payA_L);
        fusedB_kernel<10><<<NBKT, 1024, 0, stream>>>(payA_K, payA_L, offBkt,
                                                     user16, i_w,
                                                     stack_i, item_mean, I_N);
    } else {
        size_t stack_bytes = sizeof(float) * (size_t)B_N * (U_N + I_N) * D_N;
        hipMemsetAsync(stack_u, 0, stack_bytes, stream);
        long long nthreads = (long long)EDGES * 16;
        int nblocks = (int)((nthreads + 255) / 256);
        scatter_atomic_kernel<<<nblocks, 256, 0, stream>>>(
            user_emb, item_emb, rows, cols, vals, stack_u, stack_i);
        transform_kernel<U_N><<<U_N, 64, 0, stream>>>(stack_u, u_w, user_mean);
        transform_kernel<I_N><<<I_N, 64, 0, stream>>>(stack_i, i_w, item_mean);
    }
}

// Round 16
// 996.291 us; speedup vs baseline: 1.3252x; 1.3252x over previous
//
#include <hip/hip_runtime.h>

#define U_N 100000
#define I_N 50000
#define D_N 64
#define B_N 4
#define E_N 2000000

#define EDGES   (B_N * E_N)            // 8,000,000 edge-entries per side
#define NSC_U   (U_N / 8)              // 12,500 chunks (8 rows x 4 behaviors)
#define NSC_I   (I_N / 8)              // 6,250 item chunks
#define CROW    12544                  // padded chunk-row length (>= NSC_U)
#define NBLK    256                    // partition blocks (32 per XCD)
#define EPB     (EDGES / NBLK)         // 31,250 entries per block (exact)
#define CAP     1536                   // fused-kernel LDS sort capacity
#define SC_T    13                     // 1024*13 >= 12,500

// Bin key: bin = row*4 + behavior -> chunk = row>>3, local = ((k&7)<<2)|b.
// KEY ALGEBRA: outputs only need sigmoid(x@W); by linearity y = sum v*(emb@W),
// so we precompute embW = emb @ W (bf16) and accumulate y directly — the
// per-chunk transform stage disappears entirely.
// User side: keys=rows, gathers itemW16 = item_emb @ u_w.
// Item side: keys=cols, gathers userW16 = user_emb @ i_w.

// ---------------------------------------------------------------------------
// Pass 0: embW = emb @ W, rounded to bf16 (RNE). 32 rows per 256-thr block.
// ---------------------------------------------------------------------------
__global__ __launch_bounds__(256) void precompW_kernel(
        const float* __restrict__ emb, const float* __restrict__ W,
        unsigned short* __restrict__ out16, int nrows) {
    __shared__ float Wl[4096];           // 16 KB, W staged once per block
    int t = threadIdx.x, w = t >> 6, lane = t & 63;
    for (int i = t; i < 4096; i += 256) Wl[i] = W[i];
    __syncthreads();
    int base = blockIdx.x * 32;
#pragma unroll
    for (int it = 0; it < 8; ++it) {
        int row = base + it * 4 + w;
        float x = (row < nrows) ? emb[row * 64 + lane] : 0.f;
        float y = 0.f;
#pragma unroll 8
        for (int d = 0; d < 64; ++d)
            y = fmaf(__shfl(x, d), Wl[d * 64 + lane], y);
        if (row < nrows) {
            unsigned u = __float_as_uint(y);
            u += 0x7FFFu + ((u >> 16) & 1u);
            out16[row * 64 + lane] = (unsigned short)(u >> 16);
        }
    }
}

// ---------------------------------------------------------------------------
// Pass 1: per-(block, chunk) histogram; block lb owns entries [lb*EPB, ...).
// ---------------------------------------------------------------------------
__global__ __launch_bounds__(512) void bhist_kernel(const int* __restrict__ keys,
                                                    int nsc,
                                                    int* __restrict__ cnt) {
    __shared__ int h[CROW];
    for (int i = threadIdx.x; i < nsc; i += 512) h[i] = 0;
    __syncthreads();
    int lb = ((blockIdx.x & 7) << 5) | (blockIdx.x >> 3);
    int base = lb * EPB;
    for (int i = threadIdx.x; i < EPB; i += 512)
        atomicAdd(&h[keys[base + i] >> 3], 1);
    __syncthreads();
    int* row = cnt + (size_t)lb * CROW;
    for (int i = threadIdx.x; i < nsc; i += 512) row[i] = h[i];
}

// ---------------------------------------------------------------------------
// Pass 2: totals, exclusive scan, then counts -> per-block cursors in place.
// ---------------------------------------------------------------------------
__global__ __launch_bounds__(512) void scan_tot(const int* __restrict__ cnt,
                                                int nsc, int* __restrict__ cnt_ch) {
    int c = blockIdx.x * 512 + threadIdx.x;
    if (c >= nsc) return;
    int s = 0;
    for (int lb = 0; lb < NBLK; ++lb) s += cnt[(size_t)lb * CROW + c];
    cnt_ch[c] = s;
}

__global__ __launch_bounds__(1024) void scan_ex(const int* __restrict__ cnt_ch,
                                                int nsc, int* __restrict__ off_ch) {
    int t = threadIdx.x;
    int loc[SC_T]; int s = 0;
#pragma unroll
    for (int j = 0; j < SC_T; ++j) {
        int idx = t * SC_T + j;
        int c = (idx < nsc) ? cnt_ch[idx] : 0;
        loc[j] = s; s += c;
    }
    __shared__ int sm[1024];
    int mine = s; sm[t] = s; __syncthreads();
    for (int o = 1; o < 1024; o <<= 1) {
        int a = (t >= o) ? sm[t - o] : 0;
        __syncthreads(); sm[t] += a; __syncthreads();
    }
    int pre = sm[t] - mine;
#pragma unroll
    for (int j = 0; j < SC_T; ++j) {
        int idx = t * SC_T + j;
        if (idx < nsc) off_ch[idx] = pre + loc[j];
    }
}

__global__ __launch_bounds__(512) void scan_cur(int* __restrict__ cnt,
                                                const int* __restrict__ off_ch,
                                                int nsc) {
    int c = blockIdx.x * 512 + threadIdx.x;
    if (c >= nsc) return;
    int run = off_ch[c];
    for (int lb = 0; lb < NBLK; ++lb) {
        int v = cnt[(size_t)lb * CROW + c];
        cnt[(size_t)lb * CROW + c] = run;
        run += v;
    }
}

// ---------------------------------------------------------------------------
// Pass 3: placement, zero global atomics (LDS cursor row per block).
// pay = { local(5b)<<17 | src(17b), v (f32) }.
// ---------------------------------------------------------------------------
__global__ __launch_bounds__(512) void cplace_kernel(const int* __restrict__ keys,
                                                     const int* __restrict__ srcs,
                                                     const float* __restrict__ vals,
                                                     const int* __restrict__ cur_g,
                                                     int nsc,
                                                     uint2* __restrict__ pay) {
    __shared__ int cur[CROW];
    int lb = ((blockIdx.x & 7) << 5) | (blockIdx.x >> 3);
    const int* row = cur_g + (size_t)lb * CROW;
    for (int i = threadIdx.x; i < nsc; i += 512) cur[i] = row[i];
    __syncthreads();
    int base = lb * EPB;
    int b = lb >> 6;                     // behavior: 64 blocks per behavior
    for (int i = threadIdx.x; i < EPB; i += 512) {
        int gi = base + i;
        int k = keys[gi];
        float v = vals[gi];
        int src = srcs[gi];
        int pos = atomicAdd(&cur[k >> 3], 1);
        pay[pos] = make_uint2(((unsigned)(((k & 7) << 2) | b) << 17) | (unsigned)src,
                              __float_as_uint(v));
    }
}

// ---------------------------------------------------------------------------
// Pass 4 (fused): LDS counting-sort -> quad-row register accumulate of y
// (directly from embW16; no transform stage) -> quarter-reduce -> sigmoid ->
// float4 stores. LDS ~12.5 KB -> 4 blocks/CU.
// ---------------------------------------------------------------------------
__global__ __launch_bounds__(512) void fused_kernel(
        const unsigned short* __restrict__ embW16,
        const int* __restrict__ off_ch,
        const int* __restrict__ cnt_ch,
        const uint2* __restrict__ pay,
        float* __restrict__ embs,        // [B][nrows][64] <- sigmoid(y)
        float* __restrict__ mean_out,    // [nrows][64]    <- sigmoid(mean y)
        int nrows) {
    int g = blockIdx.x;
    int start = off_ch[g], n = cnt_ch[g];
    int t = threadIdx.x, w = t >> 6, lane = t & 63;

    __shared__ uint2 st2[CAP];           // 12.3 KB sorted payload
    __shared__ int c32[32];
    __shared__ int bstart[33];
    float* ys = (float*)st2;             // fallback-path alias (8 KB <= st2)

    if (n <= CAP) {
        if (t < 32) c32[t] = 0;
        __syncthreads();
        for (int i = t; i < n; i += 512)
            atomicAdd(&c32[pay[start + i].x >> 17], 1);
        __syncthreads();
        if (t == 0) {
            int s = 0;
            for (int b2 = 0; b2 < 32; ++b2) {
                bstart[b2] = s; s += c32[b2]; c32[b2] = bstart[b2];
            }
            bstart[32] = s;
        }
        __syncthreads();
        for (int i = t; i < n; i += 512) {
            uint2 p = pay[start + i];
            int pos = atomicAdd(&c32[p.x >> 17], 1);
            st2[pos] = p;
        }
        __syncthreads();

        // Quad-row accumulate of y: quarter qt handles entry j+qt; lane
        // covers dims 4*ql..4*ql+3 via one dwordx2 load from embW16.
        int qt = lane >> 4, ql = lane & 15;
        float4 a0, a1, a2, a3;
#define ACC_BIN(AQ, Q)                                                        \
        {                                                                     \
            int s0 = bstart[w * 4 + (Q)], s1 = bstart[w * 4 + (Q) + 1];       \
            AQ = make_float4(0.f, 0.f, 0.f, 0.f);                             \
            for (int j = s0; j < s1; j += 4) {                                \
                int idx = j + qt;                                             \
                int jj = idx < s1 ? idx : s1 - 1;                             \
                uint2 p = st2[jj];                                            \
                float v = (idx < s1) ? __uint_as_float(p.y) : 0.f;            \
                uint2 x = *((const uint2*)(embW16 +                           \
                              (size_t)(p.x & 0x1FFFFu) * 64) + ql);           \
                AQ.x = fmaf(v, __uint_as_float(x.x << 16), AQ.x);             \
                AQ.y = fmaf(v, __uint_as_float(x.x & 0xFFFF0000u), AQ.y);     \
                AQ.z = fmaf(v, __uint_as_float(x.y << 16), AQ.z);             \
                AQ.w = fmaf(v, __uint_as_float(x.y & 0xFFFF0000u), AQ.w);     \
            }                                                                 \
            AQ.x += __shfl_xor(AQ.x, 16); AQ.x += __shfl_xor(AQ.x, 32);       \
            AQ.y += __shfl_xor(AQ.y, 16); AQ.y += __shfl_xor(AQ.y, 32);       \
            AQ.z += __shfl_xor(AQ.z, 16); AQ.z += __shfl_xor(AQ.z, 32);       \
            AQ.w += __shfl_xor(AQ.w, 16); AQ.w += __shfl_xor(AQ.w, 32);       \
        }
        ACC_BIN(a0, 0)
        ACC_BIN(a1, 1)
        ACC_BIN(a2, 2)
        ACC_BIN(a3, 3)
#undef ACC_BIN
        // All quarters hold full sums; qt==0 lanes (ql=0..15) store float4
        // at dims 4*ql..4*ql+3 -> one coalesced 256B store per output row.
        if (qt == 0) {
            int row = g * 8 + w;
            float4 yq[4] = {a0, a1, a2, a3};
#pragma unroll
            for (int q = 0; q < 4; ++q) {
                float4 s4;
                s4.x = 1.f / (1.f + __expf(-yq[q].x));
                s4.y = 1.f / (1.f + __expf(-yq[q].y));
                s4.z = 1.f / (1.f + __expf(-yq[q].z));
                s4.w = 1.f / (1.f + __expf(-yq[q].w));
                *(float4*)&embs[((long long)q * nrows + row) * 64 + 4 * ql] = s4;
            }
            float4 m4;
            m4.x = 0.25f * (a0.x + a1.x + a2.x + a3.x);
            m4.y = 0.25f * (a0.y + a1.y + a2.y + a3.y);
            m4.z = 0.25f * (a0.z + a1.z + a2.z + a3.z);
            m4.w = 0.25f * (a0.w + a1.w + a2.w + a3.w);
            m4.x = 1.f / (1.f + __expf(-m4.x));
            m4.y = 1.f / (1.f + __expf(-m4.y));
            m4.z = 1.f / (1.f + __expf(-m4.z));
            m4.w = 1.f / (1.f + __expf(-m4.w));
            *(float4*)&mean_out[(long long)row * 64 + 4 * ql] = m4;
        }
    } else {
        // Fallback (never for this input): LDS-atomic y accumulate.
        for (int i = t; i < 2048; i += 512) ys[i] = 0.f;
        __syncthreads();
        for (int j = w; j < n; j += 8) {
            uint2 pv = pay[start + j];
            float x = __uint_as_float(
                (unsigned)embW16[(size_t)(pv.x & 0x1FFFFu) * 64 + lane] << 16);
            atomicAdd(&ys[(pv.x >> 17) * 64 + lane],
                      __uint_as_float(pv.y) * x);
        }
        __syncthreads();
        int row = g * 8 + w;
        float y[4];
#pragma unroll
        for (int q = 0; q < 4; ++q) {
            y[q] = ys[(w * 4 + q) * 64 + lane];
            embs[((long long)q * nrows + row) * 64 + lane] =
                1.f / (1.f + __expf(-y[q]));
        }
        float m = 0.25f * (y[0] + y[1] + y[2] + y[3]);
        mean_out[(long long)row * 64 + lane] = 1.f / (1.f + __expf(-m));
    }
}

// ---------------------------------------------------------------------------
// Deep fallback: atomic scatter + separate transform (only if ws too small).
// ---------------------------------------------------------------------------
__global__ void scatter_atomic_kernel(const float* __restrict__ user_emb,
                                      const float* __restrict__ item_emb,
                                      const int* __restrict__ rows,
                                      const int* __restrict__ cols,
                                      const float* __restrict__ vals,
                                      float* __restrict__ stack_u,
                                      float* __restrict__ stack_i) {
    long long tid = (long long)blockIdx.x * blockDim.x + threadIdx.x;
    long long e  = tid >> 4;
    int lane = (int)(tid & 15);
    if (e >= (long long)EDGES) return;
    int b = (int)(e / E_N);
    int r = rows[e];
    int c = cols[e];
    float v = vals[e];
    const float4* irow = (const float4*)(item_emb + (long long)c * D_N);
    const float4* urow = (const float4*)(user_emb + (long long)r * D_N);
    float4 iv = irow[lane];
    float4 uv = urow[lane];
    float* du = stack_u + ((long long)b * U_N + r) * D_N + lane * 4;
    float* di = stack_i + ((long long)b * I_N + c) * D_N + lane * 4;
    atomicAdd(du + 0, v * iv.x);
    atomicAdd(du + 1, v * iv.y);
    atomicAdd(du + 2, v * iv.z);
    atomicAdd(du + 3, v * iv.w);
    atomicAdd(di + 0, v * uv.x);
    atomicAdd(di + 1, v * uv.y);
    atomicAdd(di + 2, v * uv.z);
    atomicAdd(di + 3, v * uv.w);
}

template <int NROWS>
__global__ __launch_bounds__(64) void transform_kernel(
        float* __restrict__ stack,
        const float* __restrict__ W,
        float* __restrict__ mean_out) {
    const int row = blockIdx.x;
    const int j   = threadIdx.x;
    __shared__ float xs[B_N][D_N];
#pragma unroll
    for (int b = 0; b < B_N; ++b)
        xs[b][j] = stack[((long long)b * NROWS + row) * D_N + j];
    __syncthreads();
    float acc[B_N] = {0.f, 0.f, 0.f, 0.f};
#pragma unroll 8
    for (int d = 0; d < D_N; ++d) {
        float w = W[d * D_N + j];
#pragma unroll
        for (int b = 0; b < B_N; ++b)
            acc[b] += xs[b][d] * w;
    }
    float m = 0.25f * (acc[0] + acc[1] + acc[2] + acc[3]);
#pragma unroll
    for (int b = 0; b < B_N; ++b)
        stack[((long long)b * NROWS + row) * D_N + j] =
            1.0f / (1.0f + __expf(-acc[b]));
    mean_out[(long long)row * D_N + j] = 1.0f / (1.0f + __expf(-m));
}

// ---------------------------------------------------------------------------
extern "C" void kernel_launch(void* const* d_in, const int* in_sizes, int n_in,
                              void* d_out, int out_size, void* d_ws, size_t ws_size,
                              hipStream_t stream) {
    const float* user_emb = (const float*)d_in[0];
    const float* item_emb = (const float*)d_in[1];
    const int*   rows     = (const int*)  d_in[2];
    const int*   cols     = (const int*)  d_in[3];
    const float* vals     = (const float*)d_in[4];
    const float* u_w      = (const float*)d_in[5];
    const float* i_w      = (const float*)d_in[6];

    float* out = (float*)d_out;
    float* user_mean = out;
    float* item_mean = out + (long long)U_N * D_N;
    float* stack_u   = item_mean + (long long)I_N * D_N;     // user_embs out
    float* stack_i   = stack_u + (long long)B_N * U_N * D_N; // item_embs out

    // Workspace: cnt [NBLK][CROW] | cnt_ch | off_ch | pay [EDGES] |
    //            userW16 [U*64] | itemW16 [I*64]   (~96 MB)
    int* cnt    = (int*)d_ws;
    int* cnt_ch = cnt + (size_t)NBLK * CROW;
    int* off_ch = cnt_ch + CROW;
    uint2* pay  = (uint2*)(off_ch + CROW);
    unsigned short* userW16 = (unsigned short*)(pay + EDGES);  // user_emb @ i_w
    unsigned short* itemW16 = userW16 + (size_t)U_N * D_N;     // item_emb @ u_w
    size_t needed = ((size_t)NBLK * CROW + 2 * CROW) * 4 +
                    (size_t)EDGES * 8 + (size_t)(U_N + I_N) * D_N * 2;

    if (ws_size >= needed) {
        precompW_kernel<<<(I_N + 31) / 32, 256, 0, stream>>>(item_emb, u_w,
                                                             itemW16, I_N);
        precompW_kernel<<<(U_N + 31) / 32, 256, 0, stream>>>(user_emb, i_w,
                                                             userW16, U_N);
        // ---- user side: keys=rows, gathers itemW16 ----
        bhist_kernel<<<NBLK, 512, 0, stream>>>(rows, NSC_U, cnt);
        scan_tot<<<(NSC_U + 511) / 512, 512, 0, stream>>>(cnt, NSC_U, cnt_ch);
        scan_ex<<<1, 1024, 0, stream>>>(cnt_ch, NSC_U, off_ch);
        scan_cur<<<(NSC_U + 511) / 512, 512, 0, stream>>>(cnt, off_ch, NSC_U);
        cplace_kernel<<<NBLK, 512, 0, stream>>>(rows, cols, vals, cnt, NSC_U, pay);
        fused_kernel<<<NSC_U, 512, 0, stream>>>(itemW16, off_ch, cnt_ch, pay,
                                                stack_u, user_mean, U_N);
        // ---- item side: keys=cols, gathers userW16 ----
        bhist_kernel<<<NBLK, 512, 0, stream>>>(cols, NSC_I, cnt);
        scan_tot<<<(NSC_I + 511) / 512, 512, 0, stream>>>(cnt, NSC_I, cnt_ch);
        scan_ex<<<1, 1024, 0, stream>>>(cnt_ch, NSC_I, off_ch);
        scan_cur<<<(NSC_I + 511) / 512, 512, 0, stream>>>(cnt, off_ch, NSC_I);
        cplace_kernel<<<NBLK, 512, 0, stream>>>(cols, rows, vals, cnt, NSC_I, pay);
        fused_kernel<<<NSC_I, 512, 0, stream>>>(userW16, off_ch, cnt_ch, pay,
                                                stack_i, item_mean, I_N);
    } else {
        size_t stack_bytes = sizeof(float) * (size_t)B_N * (U_N + I_N) * D_N;
        hipMemsetAsync(stack_u, 0, stack_bytes, stream);
        long long nthreads = (long long)EDGES * 16;
        int nblocks = (int)((nthreads + 255) / 256);
        scatter_atomic_kernel<<<nblocks, 256, 0, stream>>>(
            user_emb, item_emb, rows, cols, vals, stack_u, stack_i);
        transform_kernel<U_N><<<U_N, 64, 0, stream>>>(stack_u, u_w, user_mean);
        transform_kernel<I_N><<<I_N, 64, 0, stream>>>(stack_i, i_w, item_mean);
    }
}